// Round 14
// baseline (205.372 us; speedup 1.0000x reference)
//
#include <hip/hip_runtime.h>

// GQA prefill block, MI355X gfx950. Round 13: BK 64->128 in both GEMMs
// (halve barrier count, 2x MFMA per barrier; LDS 32 KB -> proj 5 blocks/CU,
// oproj still grid-limited 4/CU). Flash unchanged (round-12 version).
// 3 dispatches: proj | flash | oproj.

typedef __bf16 bf16;
typedef __attribute__((ext_vector_type(8))) __bf16 bf16x8;
typedef __attribute__((ext_vector_type(4))) float f32x4;

#define MFMA(a, b, c) __builtin_amdgcn_mfma_f32_16x16x32_bf16((a), (b), (c), 0, 0, 0)
#define GLOAD_LDS16(g, l)                                        \
  __builtin_amdgcn_global_load_lds(                              \
      (const __attribute__((address_space(1))) void*)(g),        \
      (__attribute__((address_space(3))) void*)(l), 16, 0, 0)

__device__ __forceinline__ bool is_bf16_input(const void* cosRaw) {
  return ((const unsigned short*)cosRaw)[0] == 0x3F80;  // cos(0)=1.0 bf16
}
__device__ __forceinline__ float rdval(const void* p, int idx, bool isbf) {
  return isbf ? (float)((const bf16*)p)[idx] : ((const float*)p)[idx];
}

// Stage 4 rows x 128 cols into LDS block at lsbase (row-major, 128-elem rows,
// chunk pos p holds source chunk p^(row&7)). One wave per call; HW scatters
// lane -> lsbase + lane*16B. Source bf16 (DMA) or fp32 (convert+ds_write).
__device__ __forceinline__ void stage4x128(const void* src, int rowbase,
                                           int ko, int lane, bf16* lsbase,
                                           bool isbf) {
  const int rloc = lane >> 4;                 // 0..3
  const int row = rowbase + rloc;             // global row
  const int g = (lane & 15) ^ (row & 7);      // swizzled source chunk
  if (isbf) {
    GLOAD_LDS16(&((const bf16*)src)[(size_t)row * 1024 + ko + g * 8], lsbase);
  } else {
    const float* fp = &((const float*)src)[(size_t)row * 1024 + ko + g * 8];
    float4 f0 = *(const float4*)fp;
    float4 f1 = *(const float4*)(fp + 4);
    bf16x8 o;
    o[0] = (bf16)f0.x; o[1] = (bf16)f0.y; o[2] = (bf16)f0.z; o[3] = (bf16)f0.w;
    o[4] = (bf16)f1.x; o[5] = (bf16)f1.y; o[6] = (bf16)f1.z; o[7] = (bf16)f1.w;
    *(bf16x8*)&lsbase[lane * 8] = o;
  }
}

// ---------------------------------------------------------------------------
// Fused q/k/v projection. C[4096][1536] = x @ [wq;wk;wv]^T, 64m x 64n tile,
// BK=128 (8 K-iters, 16 barriers total). LDS 32 KB -> 5 blocks/CU; grid 1536.
// XCD swizzle: mb%8==xcd. nb 0..15 q (norm+rope+1/8 -> qp), 16..19 k
// (norm+rope -> kp), 20..23 v (block LDS transpose -> vt (B,KV,64,T)).
// ---------------------------------------------------------------------------
__global__ __launch_bounds__(256, 5) void proj_kernel(
    const void* __restrict__ xraw, const void* __restrict__ wqraw,
    const void* __restrict__ wkraw, const void* __restrict__ wvraw,
    bf16* __restrict__ qp, bf16* __restrict__ kp, bf16* __restrict__ vt,
    const void* __restrict__ cosraw, const void* __restrict__ sinraw,
    const void* __restrict__ qnraw, const void* __restrict__ knraw) {
  __shared__ bf16 As[64 * 128];   // 16 KB
  __shared__ bf16 Bs[64 * 128];   // 16 KB

  const int idx = (int)blockIdx.x;     // 0..1535
  const int xcd = idx & 7;
  const int jj = idx >> 3;             // 0..191
  const int mb = (jj & 7) * 8 + xcd;   // 0..63
  const int nb = jj >> 3;              // 0..23
  const int n0 = nb * 64;
  const int m0 = mb * 64;

  const int tid = threadIdx.x;
  const int wave = tid >> 6;
  const int lane = tid & 63;
  const int q16 = lane & 15;
  const int quad = lane >> 4;
  const int wm = wave * 16;
  const int x7 = q16 & 7;
  const bool isbf = is_bf16_input(cosraw);

  const void* wsrc;
  int nr0;
  if (nb < 16)      { wsrc = wqraw; nr0 = n0; }
  else if (nb < 20) { wsrc = wkraw; nr0 = n0 - 1024; }
  else              { wsrc = wvraw; nr0 = n0 - 1280; }

  f32x4 acc[4];
#pragma unroll
  for (int nt = 0; nt < 4; ++nt) acc[nt] = (f32x4){0.f, 0.f, 0.f, 0.f};

  for (int kt = 0; kt < 8; ++kt) {
    const int ko = kt * 128;
#pragma unroll
    for (int i = 0; i < 4; ++i) {
      int rb = wave * 16 + i * 4;
      stage4x128(xraw, m0 + rb, ko, lane, &As[rb * 128], isbf);
      stage4x128(wsrc, nr0 + rb, ko, lane, &Bs[rb * 128], isbf);
    }
    __syncthreads();   // staging complete

#pragma unroll
    for (int s = 0; s < 4; ++s) {
      const int p = ((s * 4 + quad) ^ x7) * 8;
      bf16x8 a0 = *(const bf16x8*)&As[(wm + q16) * 128 + p];
#pragma unroll
      for (int nt = 0; nt < 4; ++nt) {
        bf16x8 b = *(const bf16x8*)&Bs[(nt * 16 + q16) * 128 + p];
        acc[nt] = MFMA(a0, b, acc[nt]);
      }
    }
    __syncthreads();   // LDS reads done before next stage overwrites
  }

  if (nb < 20) {
    // q or k head: RMSNorm + RoPE
    const void* nwp = (nb < 16) ? qnraw : knraw;
    const float osc = (nb < 16) ? 0.125f : 1.0f;
    float wd[4];
#pragma unroll
    for (int nt = 0; nt < 4; ++nt) wd[nt] = rdval(nwp, nt * 16 + q16, isbf);

#pragma unroll
    for (int r = 0; r < 4; ++r) {
      float p = acc[0][r] * acc[0][r] + acc[1][r] * acc[1][r] +
                acc[2][r] * acc[2][r] + acc[3][r] * acc[3][r];
#pragma unroll
      for (int off = 8; off >= 1; off >>= 1) p += __shfl_xor(p, off);
      float rms = rsqrtf(p * (1.0f / 64.0f) + 1e-6f);

      int row = m0 + wm + quad * 4 + r;
      int t = row & 2047;
      float c0 = rdval(cosraw, t * 32 + q16, isbf);
      float c1 = rdval(cosraw, t * 32 + 16 + q16, isbf);
      float s0 = rdval(sinraw, t * 32 + q16, isbf);
      float s1 = rdval(sinraw, t * 32 + 16 + q16, isbf);

      float v0 = acc[0][r] * rms * wd[0];
      float v1 = acc[1][r] * rms * wd[1];
      float v2 = acc[2][r] * rms * wd[2];
      float v3 = acc[3][r] * rms * wd[3];

      bf16* op = (nb < 16) ? &qp[(size_t)row * 1024 + nb * 64]
                           : &kp[(size_t)row * 256 + (nb - 16) * 64];
      op[0 * 16 + q16] = (bf16)((v0 * c0 - v2 * s0) * osc);
      op[1 * 16 + q16] = (bf16)((v1 * c1 - v3 * s1) * osc);
      op[2 * 16 + q16] = (bf16)((v2 * c0 + v0 * s0) * osc);
      op[3 * 16 + q16] = (bf16)((v3 * c1 + v1 * s1) * osc);
    }
  } else {
    // v head: block transpose 64(t) x 64(d) via As, then coalesced writeout
    const int vh = nb - 20;
    const int b = m0 >> 11;
    const int tbase = m0 & 2047;
#pragma unroll
    for (int nt = 0; nt < 4; ++nt)
#pragma unroll
      for (int r = 0; r < 4; ++r)
        As[(wm + quad * 4 + r) * 64 + nt * 16 + q16] = (bf16)acc[nt][r];
    __syncthreads();
#pragma unroll
    for (int rep = 0; rep < 2; ++rep) {
      int c = tid + 256 * rep;     // 0..511
      int d = c >> 3;              // 0..63
      int t8 = (c & 7) * 8;
      bf16x8 pk;
#pragma unroll
      for (int j = 0; j < 8; ++j) pk[j] = As[(t8 + j) * 64 + d];
      *(bf16x8*)&vt[(((size_t)(b * 4 + vh)) * 64 + d) * 2048 + tbase + t8] = pk;
    }
  }
}

// ---------------------------------------------------------------------------
// Flash attention v6 (round-12 version, unchanged): 2 heads/block, 4 waves x
// 16 queries, 64-key LDS-dbuf tiles, fixed-max softmax exp(S-9), l via
// ones-MFMA, XOR-swizzled LDS, qblk = z ? 31-x : x.
// ---------------------------------------------------------------------------
__global__ __launch_bounds__(256, 2) void flash_kernel(
    const bf16* __restrict__ qp, const bf16* __restrict__ kp,
    const bf16* __restrict__ vt, bf16* __restrict__ attn) {
  const int qblk = blockIdx.z ? 31 - (int)blockIdx.x : (int)blockIdx.x;
  const int hp = blockIdx.y;
  const int b = blockIdx.z;
  const int h0 = hp * 2;
  const int kvh = hp >> 1;
  const int tid = threadIdx.x;
  const int wave = tid >> 6;
  const int lane = tid & 63;
  const int q16 = lane & 15;
  const int quad = lane >> 4;
  const int r7 = q16 & 7;
  const int t0 = qblk * 64 + wave * 16;

  __shared__ bf16 Ks[2][64 * 64];
  __shared__ bf16 Vs[2][64 * 64];
  __shared__ bf16 Pl[4][2][16 * 64];

  bf16x8 qa[2][2];
#pragma unroll
  for (int hd = 0; hd < 2; ++hd) {
    const bf16* qrow =
        qp + (((size_t)(b * 2048 + t0 + q16)) * 16 + h0 + hd) * 64;
    qa[hd][0] = *(const bf16x8*)(qrow + quad * 8);
    qa[hd][1] = *(const bf16x8*)(qrow + 32 + quad * 8);
  }

  bf16x8 ones;
#pragma unroll
  for (int j = 0; j < 8; ++j) ones[j] = (bf16)1.0f;

  f32x4 O[2][4], l4[2];
#pragma unroll
  for (int hd = 0; hd < 2; ++hd) {
#pragma unroll
    for (int nt = 0; nt < 4; ++nt) O[hd][nt] = (f32x4){0.f, 0.f, 0.f, 0.f};
    l4[hd] = (f32x4){0.f, 0.f, 0.f, 0.f};
  }

  const int ntile = qblk + 1;

  bf16x8 kr[2], vr[2];
  const int cr = tid * 2;
  const int krow = cr >> 3;
  const size_t kgbase = (((size_t)(b * 2048) + krow) * 4 + kvh) * 64;
  const size_t vgbase = ((size_t)(b * 4 + kvh) * 64 + krow) * 2048;

  auto gload = [&](int tk) {
#pragma unroll
    for (int rep = 0; rep < 2; ++rep) {
      int ch = (cr + rep) & 7;
      kr[rep] = *(const bf16x8*)&kp[kgbase + (size_t)(tk * 64) * 256 + ch * 8];
      vr[rep] = *(const bf16x8*)&vt[vgbase + tk * 64 + ch * 8];
    }
  };
  auto swrite = [&](int bb) {
#pragma unroll
    for (int rep = 0; rep < 2; ++rep) {
      int ch = (cr + rep) & 7;
      int pos = (ch ^ (krow & 7)) * 8;
      *(bf16x8*)&Ks[bb][krow * 64 + pos] = kr[rep];
      *(bf16x8*)&Vs[bb][krow * 64 + pos] = vr[rep];
    }
  };

  gload(0);

  for (int t = 0; t < ntile; ++t) {
    const int bb = t & 1;
    const int kbase = t * 64;
    swrite(bb);
    __syncthreads();
    if (t + 1 < ntile) gload(t + 1);

    bf16x8 vbr[2][4];
#pragma unroll
    for (int kh = 0; kh < 2; ++kh)
#pragma unroll
      for (int nt = 0; nt < 4; ++nt) {
        const bf16* vr0 = &Vs[bb][(nt * 16 + q16) * 64];
        vbr[kh][nt] = *(const bf16x8*)&vr0[((kh * 4 + quad) ^ r7) * 8];
      }

    bf16x8 kb[4][2];
#pragma unroll
    for (int kt = 0; kt < 4; ++kt) {
      const bf16* kr0 = &Ks[bb][(kt * 16 + q16) * 64];
      kb[kt][0] = *(const bf16x8*)&kr0[(quad ^ r7) * 8];
      kb[kt][1] = *(const bf16x8*)&kr0[((quad + 4) ^ r7) * 8];
    }

    const bool edge = (kbase + 63 > t0);
#pragma unroll
    for (int hd = 0; hd < 2; ++hd) {
      f32x4 s[4];
#pragma unroll
      for (int kt = 0; kt < 4; ++kt) {
        f32x4 z = (f32x4){0.f, 0.f, 0.f, 0.f};
        z = MFMA(qa[hd][0], kb[kt][0], z);
        z = MFMA(qa[hd][1], kb[kt][1], z);
        s[kt] = z;
      }
      if (edge) {
#pragma unroll
        for (int kt = 0; kt < 4; ++kt) {
          int jt = kbase + kt * 16 + q16;
#pragma unroll
          for (int r = 0; r < 4; ++r)
            if (jt > t0 + quad * 4 + r) s[kt][r] = -1e30f;
        }
      }
#pragma unroll
      for (int kt = 0; kt < 4; ++kt)
#pragma unroll
        for (int r = 0; r < 4; ++r) s[kt][r] = __expf(s[kt][r] - 9.0f);

#pragma unroll
      for (int kt = 0; kt < 4; ++kt)
#pragma unroll
        for (int r = 0; r < 4; ++r) {
          int row = quad * 4 + r;
          int col = kt * 16 + q16;
          Pl[wave][hd][row * 64 + ((col >> 3) ^ (row & 7)) * 8 + (col & 7)] =
              (bf16)s[kt][r];
        }
    }

#pragma unroll
    for (int hd = 0; hd < 2; ++hd)
#pragma unroll
      for (int kh = 0; kh < 2; ++kh) {
        bf16x8 pa = *(const bf16x8*)&Pl[wave][hd][q16 * 64 +
                                                  (((kh * 4 + quad) ^ r7) * 8)];
#pragma unroll
        for (int nt = 0; nt < 4; ++nt)
          O[hd][nt] = MFMA(pa, vbr[kh][nt], O[hd][nt]);
        l4[hd] = MFMA(pa, ones, l4[hd]);
      }
  }

#pragma unroll
  for (int hd = 0; hd < 2; ++hd) {
    float inv[4];
#pragma unroll
    for (int r = 0; r < 4; ++r) inv[r] = 1.0f / l4[hd][r];
#pragma unroll
    for (int nt = 0; nt < 4; ++nt)
#pragma unroll
      for (int r = 0; r < 4; ++r) {
        size_t o = (((size_t)(b * 2048 + t0 + quad * 4 + r)) * 16 + h0 + hd) * 64 +
                   nt * 16 + q16;
        attn[o] = (bf16)(O[hd][nt][r] * inv[r]);
      }
  }
}

// ---------------------------------------------------------------------------
// o-projection: 64m x 64n tile, BK=128, grid 1024 (4 blocks/CU, LDS allows 5),
// XCD swizzle. Output dtype per detected input dtype.
// ---------------------------------------------------------------------------
__global__ __launch_bounds__(256, 4) void gemm_o_kernel(
    const bf16* __restrict__ A, const void* __restrict__ Wraw,
    void* __restrict__ C, const void* __restrict__ cosraw) {
  __shared__ bf16 As[64 * 128];
  __shared__ bf16 Bs[64 * 128];

  const int idx = (int)blockIdx.x;     // 0..1023
  const int xcd = idx & 7;
  const int jj = idx >> 3;             // 0..127
  const int mb = (jj & 7) * 8 + xcd;   // 0..63
  const int nb = jj >> 3;              // 0..15
  const int n0 = nb * 64;
  const int m0 = mb * 64;

  const int tid = threadIdx.x;
  const int wave = tid >> 6;
  const int lane = tid & 63;
  const int q16 = lane & 15;
  const int quad = lane >> 4;
  const int wm = wave * 16;
  const int x7 = q16 & 7;
  const bool isbf = is_bf16_input(cosraw);

  f32x4 acc[4];
#pragma unroll
  for (int nt = 0; nt < 4; ++nt) acc[nt] = (f32x4){0.f, 0.f, 0.f, 0.f};

  for (int kt = 0; kt < 8; ++kt) {
    const int ko = kt * 128;
#pragma unroll
    for (int i = 0; i < 4; ++i) {
      int rb = wave * 16 + i * 4;
      stage4x128(A, m0 + rb, ko, lane, &As[rb * 128], true);
      stage4x128(Wraw, n0 + rb, ko, lane, &Bs[rb * 128], isbf);
    }
    __syncthreads();

#pragma unroll
    for (int s = 0; s < 4; ++s) {
      const int p = ((s * 4 + quad) ^ x7) * 8;
      bf16x8 a0 = *(const bf16x8*)&As[(wm + q16) * 128 + p];
#pragma unroll
      for (int nt = 0; nt < 4; ++nt) {
        bf16x8 b = *(const bf16x8*)&Bs[(nt * 16 + q16) * 128 + p];
        acc[nt] = MFMA(a0, b, acc[nt]);
      }
    }
    __syncthreads();
  }

#pragma unroll
  for (int nt = 0; nt < 4; ++nt)
#pragma unroll
    for (int r = 0; r < 4; ++r) {
      size_t idx2 = (size_t)(m0 + wm + quad * 4 + r) * 1024 + n0 + nt * 16 + q16;
      if (isbf) ((bf16*)C)[idx2] = (bf16)acc[nt][r];
      else      ((float*)C)[idx2] = acc[nt][r];
    }
}

// ---------------------------------------------------------------------------
extern "C" void kernel_launch(void* const* d_in, const int* in_sizes, int n_in,
                              void* d_out, int out_size, void* d_ws, size_t ws_size,
                              hipStream_t stream) {
  bf16* qp = (bf16*)d_ws;                    // 4096*1024
  bf16* kp = qp + (size_t)4096 * 1024;       // 4096*256
  bf16* vt = kp + (size_t)4096 * 256;        // 4096*256
  bf16* at = vt + (size_t)4096 * 256;        // 4096*1024

  // 1) fused q/k/v projection (+ norm/rope/vtranspose, inline dtype)
  proj_kernel<<<1536, 256, 0, stream>>>(
      d_in[0], d_in[3], d_in[4], d_in[5], qp, kp, vt,
      d_in[1], d_in[2], d_in[7], d_in[8]);

  // 2) causal GQA flash attention (2 heads/block)
  flash_kernel<<<dim3(32, 8, 2), 256, 0, stream>>>(qp, kp, vt, at);

  // 3) output projection -> d_out
  gemm_o_kernel<<<1024, 256, 0, stream>>>(at, d_in[6], d_out, d_in[1]);
}

// Round 15
// 172.796 us; speedup vs baseline: 1.1885x; 1.1885x over previous
//
#include <hip/hip_runtime.h>

// GQA prefill block, MI355X gfx950. Round 14: GEMMs reverted to round-12
// (best: 64x64 BK=64, 6/4 blocks/CU). Flash v7: 1 head/block, grid 1024 =
// 4 blocks/CU (LDS 36 KB: kh-sequential 16x32 P scratch), uniform 66
// tiles/CU. 3 dispatches: proj | flash | oproj.

typedef __bf16 bf16;
typedef __attribute__((ext_vector_type(8))) __bf16 bf16x8;
typedef __attribute__((ext_vector_type(4))) float f32x4;

#define MFMA(a, b, c) __builtin_amdgcn_mfma_f32_16x16x32_bf16((a), (b), (c), 0, 0, 0)
#define GLOAD_LDS16(g, l)                                        \
  __builtin_amdgcn_global_load_lds(                              \
      (const __attribute__((address_space(1))) void*)(g),        \
      (__attribute__((address_space(3))) void*)(l), 16, 0, 0)

__device__ __forceinline__ bool is_bf16_input(const void* cosRaw) {
  return ((const unsigned short*)cosRaw)[0] == 0x3F80;  // cos(0)=1.0 bf16
}
__device__ __forceinline__ float rdval(const void* p, int idx, bool isbf) {
  return isbf ? (float)((const bf16*)p)[idx] : ((const float*)p)[idx];
}

// stage one 8-row group (8 rows x 64 cols bf16) into LDS at ls[0..511]
// (+lane*16B by HW for bf16 path), XOR-swizzled chunks.
__device__ __forceinline__ void stage_rows(const void* src, size_t rowbase,
                                           int ko, int srow, int csrc,
                                           int lane, bf16* ls, bool isbf) {
  if (isbf) {
    GLOAD_LDS16(&((const bf16*)src)[(rowbase + srow) * 1024 + ko + csrc * 8], ls);
  } else {
    const float* fp = &((const float*)src)[(rowbase + srow) * 1024 + ko + csrc * 8];
    float4 f0 = *(const float4*)fp;
    float4 f1 = *(const float4*)(fp + 4);
    bf16x8 o;
    o[0] = (bf16)f0.x; o[1] = (bf16)f0.y; o[2] = (bf16)f0.z; o[3] = (bf16)f0.w;
    o[4] = (bf16)f1.x; o[5] = (bf16)f1.y; o[6] = (bf16)f1.z; o[7] = (bf16)f1.w;
    *(bf16x8*)&ls[lane * 8] = o;
  }
}

// ---------------------------------------------------------------------------
// Fused q/k/v projection (round-12 version). 64m x 64n tile, BK=64,
// single-buffered 16 KB LDS, grid 1536 = 6 blocks/CU. XCD swizzle mb%8==xcd.
// nb 0..15 q (norm+rope+1/8 -> qp), 16..19 k (norm+rope -> kp),
// 20..23 v (block LDS transpose -> vt (B,KV,64,T)).
// ---------------------------------------------------------------------------
__global__ __launch_bounds__(256, 6) void proj_kernel(
    const void* __restrict__ xraw, const void* __restrict__ wqraw,
    const void* __restrict__ wkraw, const void* __restrict__ wvraw,
    bf16* __restrict__ qp, bf16* __restrict__ kp, bf16* __restrict__ vt,
    const void* __restrict__ cosraw, const void* __restrict__ sinraw,
    const void* __restrict__ qnraw, const void* __restrict__ knraw) {
  __shared__ bf16 As[64 * 64];   // 8 KB
  __shared__ bf16 Bs[64 * 64];   // 8 KB

  const int idx = (int)blockIdx.x;     // 0..1535
  const int xcd = idx & 7;
  const int jj = idx >> 3;             // 0..191
  const int mb = (jj & 7) * 8 + xcd;   // 0..63
  const int nb = jj >> 3;              // 0..23
  const int n0 = nb * 64;
  const int m0 = mb * 64;

  const int tid = threadIdx.x;
  const int wave = tid >> 6;
  const int lane = tid & 63;
  const int q16 = lane & 15;
  const int quad = lane >> 4;
  const int srow = lane >> 3;
  const int csrc = (lane & 7) ^ srow;
  const int wm = wave * 16;
  const int x7 = q16 & 7;
  const bool isbf = is_bf16_input(cosraw);

  const void* wsrc;
  int nr0;
  if (nb < 16)      { wsrc = wqraw; nr0 = n0; }
  else if (nb < 20) { wsrc = wkraw; nr0 = n0 - 1024; }
  else              { wsrc = wvraw; nr0 = n0 - 1280; }

  f32x4 acc[4];
#pragma unroll
  for (int nt = 0; nt < 4; ++nt) acc[nt] = (f32x4){0.f, 0.f, 0.f, 0.f};

  for (int kt = 0; kt < 16; ++kt) {
    const int ko = kt * 64;
#pragma unroll
    for (int i = 0; i < 2; ++i) {
      int rb = wave * 16 + i * 8;
      stage_rows(xraw, (size_t)(m0 + rb), ko, srow, csrc, lane, &As[rb * 64], isbf);
      stage_rows(wsrc, (size_t)(nr0 + rb), ko, srow, csrc, lane, &Bs[rb * 64], isbf);
    }
    __syncthreads();

    bf16x8 a0, a1, bfr[4][2];
    {
      const bf16* rp = &As[(wm + q16) * 64];
      a0 = *(const bf16x8*)&rp[(quad ^ x7) * 8];
      a1 = *(const bf16x8*)&rp[((quad + 4) ^ x7) * 8];
    }
#pragma unroll
    for (int nt = 0; nt < 4; ++nt) {
      const bf16* rp = &Bs[(nt * 16 + q16) * 64];
      bfr[nt][0] = *(const bf16x8*)&rp[(quad ^ x7) * 8];
      bfr[nt][1] = *(const bf16x8*)&rp[((quad + 4) ^ x7) * 8];
    }
#pragma unroll
    for (int nt = 0; nt < 4; ++nt) {
      acc[nt] = MFMA(a0, bfr[nt][0], acc[nt]);
      acc[nt] = MFMA(a1, bfr[nt][1], acc[nt]);
    }
    __syncthreads();
  }

  if (nb < 20) {
    const void* nwp = (nb < 16) ? qnraw : knraw;
    const float osc = (nb < 16) ? 0.125f : 1.0f;
    float wd[4];
#pragma unroll
    for (int nt = 0; nt < 4; ++nt) wd[nt] = rdval(nwp, nt * 16 + q16, isbf);

#pragma unroll
    for (int r = 0; r < 4; ++r) {
      float p = acc[0][r] * acc[0][r] + acc[1][r] * acc[1][r] +
                acc[2][r] * acc[2][r] + acc[3][r] * acc[3][r];
#pragma unroll
      for (int off = 8; off >= 1; off >>= 1) p += __shfl_xor(p, off);
      float rms = rsqrtf(p * (1.0f / 64.0f) + 1e-6f);

      int row = m0 + wm + quad * 4 + r;
      int t = row & 2047;
      float c0 = rdval(cosraw, t * 32 + q16, isbf);
      float c1 = rdval(cosraw, t * 32 + 16 + q16, isbf);
      float s0 = rdval(sinraw, t * 32 + q16, isbf);
      float s1 = rdval(sinraw, t * 32 + 16 + q16, isbf);

      float v0 = acc[0][r] * rms * wd[0];
      float v1 = acc[1][r] * rms * wd[1];
      float v2 = acc[2][r] * rms * wd[2];
      float v3 = acc[3][r] * rms * wd[3];

      bf16* op = (nb < 16) ? &qp[(size_t)row * 1024 + nb * 64]
                           : &kp[(size_t)row * 256 + (nb - 16) * 64];
      op[0 * 16 + q16] = (bf16)((v0 * c0 - v2 * s0) * osc);
      op[1 * 16 + q16] = (bf16)((v1 * c1 - v3 * s1) * osc);
      op[2 * 16 + q16] = (bf16)((v2 * c0 + v0 * s0) * osc);
      op[3 * 16 + q16] = (bf16)((v3 * c1 + v1 * s1) * osc);
    }
  } else {
    const int vh = nb - 20;
    const int b = m0 >> 11;
    const int tbase = m0 & 2047;
#pragma unroll
    for (int nt = 0; nt < 4; ++nt)
#pragma unroll
      for (int r = 0; r < 4; ++r)
        As[(wm + quad * 4 + r) * 64 + nt * 16 + q16] = (bf16)acc[nt][r];
    __syncthreads();
#pragma unroll
    for (int rep = 0; rep < 2; ++rep) {
      int c = tid + 256 * rep;
      int d = c >> 3;
      int t8 = (c & 7) * 8;
      bf16x8 pk;
#pragma unroll
      for (int j = 0; j < 8; ++j) pk[j] = As[(t8 + j) * 64 + d];
      *(bf16x8*)&vt[(((size_t)(b * 4 + vh)) * 64 + d) * 2048 + tbase + t8] = pk;
    }
  }
}

// ---------------------------------------------------------------------------
// Flash attention v7: 1 head/block, grid (32,16,2) = 1024 = 4 blocks/CU.
// LDS 36 KB: K/V dbuf (16+16) + per-wave 16x32 kh-sequential P scratch (4).
// Fixed-max softmax exp(S-9); l via ones-MFMA. qblk = z ? 31-x : x ->
// co-resident blocks per CU sum to exactly 66 tile-units.
// ---------------------------------------------------------------------------
__global__ __launch_bounds__(256, 4) void flash_kernel(
    const bf16* __restrict__ qp, const bf16* __restrict__ kp,
    const bf16* __restrict__ vt, bf16* __restrict__ attn) {
  const int qblk = blockIdx.z ? 31 - (int)blockIdx.x : (int)blockIdx.x;
  const int h = blockIdx.y;
  const int b = blockIdx.z;
  const int kvh = h >> 2;
  const int tid = threadIdx.x;
  const int wave = tid >> 6;
  const int lane = tid & 63;
  const int q16 = lane & 15;
  const int quad = lane >> 4;
  const int r7 = q16 & 7;
  const int t0 = qblk * 64 + wave * 16;

  __shared__ bf16 Ks[2][64 * 64];   // 16 KB
  __shared__ bf16 Vs[2][64 * 64];   // 16 KB
  __shared__ bf16 Pl[4][16 * 32];   //  4 KB, per-wave, kh-sequential

  const bf16* qrow = qp + (((size_t)(b * 2048 + t0 + q16)) * 16 + h) * 64;
  bf16x8 qa0 = *(const bf16x8*)(qrow + quad * 8);
  bf16x8 qa1 = *(const bf16x8*)(qrow + 32 + quad * 8);

  bf16x8 ones;
#pragma unroll
  for (int j = 0; j < 8; ++j) ones[j] = (bf16)1.0f;

  f32x4 O[4], l4;
#pragma unroll
  for (int nt = 0; nt < 4; ++nt) O[nt] = (f32x4){0.f, 0.f, 0.f, 0.f};
  l4 = (f32x4){0.f, 0.f, 0.f, 0.f};

  const int ntile = qblk + 1;

  bf16x8 kr[2], vr[2];
  const int cr = tid * 2;
  const int krow = cr >> 3;
  const size_t kgbase = (((size_t)(b * 2048) + krow) * 4 + kvh) * 64;
  const size_t vgbase = ((size_t)(b * 4 + kvh) * 64 + krow) * 2048;

  auto gload = [&](int tk) {
#pragma unroll
    for (int rep = 0; rep < 2; ++rep) {
      int ch = (cr + rep) & 7;
      kr[rep] = *(const bf16x8*)&kp[kgbase + (size_t)(tk * 64) * 256 + ch * 8];
      vr[rep] = *(const bf16x8*)&vt[vgbase + tk * 64 + ch * 8];
    }
  };
  auto swrite = [&](int bb) {
#pragma unroll
    for (int rep = 0; rep < 2; ++rep) {
      int ch = (cr + rep) & 7;
      int pos = (ch ^ (krow & 7)) * 8;
      *(bf16x8*)&Ks[bb][krow * 64 + pos] = kr[rep];
      *(bf16x8*)&Vs[bb][krow * 64 + pos] = vr[rep];
    }
  };

  gload(0);

  for (int t = 0; t < ntile; ++t) {
    const int bb = t & 1;
    const int kbase = t * 64;
    swrite(bb);
    __syncthreads();
    if (t + 1 < ntile) gload(t + 1);

    // S = Q K^T over 4 key subtiles of 16
    f32x4 s[4];
#pragma unroll
    for (int kt = 0; kt < 4; ++kt) {
      const bf16* kr0 = &Ks[bb][(kt * 16 + q16) * 64];
      bf16x8 kb0 = *(const bf16x8*)&kr0[(quad ^ r7) * 8];
      bf16x8 kb1 = *(const bf16x8*)&kr0[((quad + 4) ^ r7) * 8];
      f32x4 z = (f32x4){0.f, 0.f, 0.f, 0.f};
      z = MFMA(qa0, kb0, z);
      z = MFMA(qa1, kb1, z);
      s[kt] = z;
    }

    if (kbase + 63 > t0) {
#pragma unroll
      for (int kt = 0; kt < 4; ++kt) {
        int jt = kbase + kt * 16 + q16;
#pragma unroll
        for (int r = 0; r < 4; ++r)
          if (jt > t0 + quad * 4 + r) s[kt][r] = -1e30f;
      }
    }

#pragma unroll
    for (int kt = 0; kt < 4; ++kt)
#pragma unroll
      for (int r = 0; r < 4; ++r) s[kt][r] = __expf(s[kt][r] - 9.0f);

    // kh-sequential P roundtrip (16x32 per-wave scratch) + PV
#pragma unroll
    for (int kh = 0; kh < 2; ++kh) {
#pragma unroll
      for (int ct = 0; ct < 2; ++ct) {
        const int kt = kh * 2 + ct;
#pragma unroll
        for (int r = 0; r < 4; ++r) {
          int row = quad * 4 + r;
          int col = ct * 16 + q16;                  // 0..31
          Pl[wave][row * 32 + (((col >> 3) ^ (row & 3)) * 8) + (col & 7)] =
              (bf16)s[kt][r];
        }
      }
      bf16x8 pa = *(const bf16x8*)&Pl[wave][q16 * 32 + ((quad ^ (q16 & 3)) * 8)];
#pragma unroll
      for (int nt = 0; nt < 4; ++nt) {
        const bf16* vr0 = &Vs[bb][(nt * 16 + q16) * 64];
        bf16x8 vb = *(const bf16x8*)&vr0[((kh * 4 + quad) ^ r7) * 8];
        O[nt] = MFMA(pa, vb, O[nt]);
      }
      l4 = MFMA(pa, ones, l4);
    }
  }

  float inv[4];
#pragma unroll
  for (int r = 0; r < 4; ++r) inv[r] = 1.0f / l4[r];
#pragma unroll
  for (int nt = 0; nt < 4; ++nt)
#pragma unroll
    for (int r = 0; r < 4; ++r) {
      size_t o = (((size_t)(b * 2048 + t0 + quad * 4 + r)) * 16 + h) * 64 +
                 nt * 16 + q16;
      attn[o] = (bf16)(O[nt][r] * inv[r]);
    }
}

// ---------------------------------------------------------------------------
// o-projection (round-12 version): 64m x 64n BK=64 single-buffered,
// grid 1024 (4 blocks/CU), XCD swizzle. Output dtype per detected dtype.
// ---------------------------------------------------------------------------
__global__ __launch_bounds__(256, 6) void gemm_o_kernel(
    const bf16* __restrict__ A, const void* __restrict__ Wraw,
    void* __restrict__ C, const void* __restrict__ cosraw) {
  __shared__ bf16 As[64 * 64];
  __shared__ bf16 Bs[64 * 64];

  const int idx = (int)blockIdx.x;     // 0..1023
  const int xcd = idx & 7;
  const int jj = idx >> 3;             // 0..127
  const int mb = (jj & 7) * 8 + xcd;   // 0..63
  const int nb = jj >> 3;              // 0..15
  const int n0 = nb * 64;
  const int m0 = mb * 64;

  const int tid = threadIdx.x;
  const int wave = tid >> 6;
  const int lane = tid & 63;
  const int q16 = lane & 15;
  const int quad = lane >> 4;
  const int srow = lane >> 3;
  const int csrc = (lane & 7) ^ srow;
  const int wm = wave * 16;
  const int x7 = q16 & 7;
  const bool isbf = is_bf16_input(cosraw);

  f32x4 acc[4];
#pragma unroll
  for (int nt = 0; nt < 4; ++nt) acc[nt] = (f32x4){0.f, 0.f, 0.f, 0.f};

  for (int kt = 0; kt < 16; ++kt) {
    const int ko = kt * 64;
#pragma unroll
    for (int i = 0; i < 2; ++i) {
      int rb = wave * 16 + i * 8;
      GLOAD_LDS16(&A[(size_t)(m0 + rb + srow) * 1024 + ko + csrc * 8],
                  &As[rb * 64]);
      stage_rows(Wraw, (size_t)(n0 + rb), ko, srow, csrc, lane, &Bs[rb * 64], isbf);
    }
    __syncthreads();

    bf16x8 a0, a1, bfr[4][2];
    {
      const bf16* rp = &As[(wm + q16) * 64];
      a0 = *(const bf16x8*)&rp[(quad ^ x7) * 8];
      a1 = *(const bf16x8*)&rp[((quad + 4) ^ x7) * 8];
    }
#pragma unroll
    for (int nt = 0; nt < 4; ++nt) {
      const bf16* rp = &Bs[(nt * 16 + q16) * 64];
      bfr[nt][0] = *(const bf16x8*)&rp[(quad ^ x7) * 8];
      bfr[nt][1] = *(const bf16x8*)&rp[((quad + 4) ^ x7) * 8];
    }
#pragma unroll
    for (int nt = 0; nt < 4; ++nt) {
      acc[nt] = MFMA(a0, bfr[nt][0], acc[nt]);
      acc[nt] = MFMA(a1, bfr[nt][1], acc[nt]);
    }
    __syncthreads();
  }

#pragma unroll
  for (int nt = 0; nt < 4; ++nt)
#pragma unroll
    for (int r = 0; r < 4; ++r) {
      size_t idx2 = (size_t)(m0 + wm + quad * 4 + r) * 1024 + n0 + nt * 16 + q16;
      if (isbf) ((bf16*)C)[idx2] = (bf16)acc[nt][r];
      else      ((float*)C)[idx2] = acc[nt][r];
    }
}

// ---------------------------------------------------------------------------
extern "C" void kernel_launch(void* const* d_in, const int* in_sizes, int n_in,
                              void* d_out, int out_size, void* d_ws, size_t ws_size,
                              hipStream_t stream) {
  bf16* qp = (bf16*)d_ws;                    // 4096*1024
  bf16* kp = qp + (size_t)4096 * 1024;       // 4096*256
  bf16* vt = kp + (size_t)4096 * 256;        // 4096*256
  bf16* at = vt + (size_t)4096 * 256;        // 4096*1024

  // 1) fused q/k/v projection (+ norm/rope/vtranspose, inline dtype)
  proj_kernel<<<1536, 256, 0, stream>>>(
      d_in[0], d_in[3], d_in[4], d_in[5], qp, kp, vt,
      d_in[1], d_in[2], d_in[7], d_in[8]);

  // 2) causal GQA flash attention (1 head/block, 4 blocks/CU)
  flash_kernel<<<dim3(32, 16, 2), 256, 0, stream>>>(qp, kp, vt, at);

  // 3) output projection -> d_out
  gemm_o_kernel<<<1024, 256, 0, stream>>>(at, d_in[6], d_out, d_in[1]);
}